// Round 3
// baseline (369.069 us; speedup 1.0000x reference)
//
#include <hip/hip_runtime.h>
#include <hip/hip_bf16.h>
#include <stdint.h>

typedef __attribute__((ext_vector_type(8))) short s16x8;     // bf16 MFMA A/B frag (4 VGPRs)
typedef __attribute__((ext_vector_type(16))) float f32x16;   // 32x32 MFMA C/D frag
typedef __attribute__((ext_vector_type(4))) unsigned short us4;

// ---- bf16 round-to-nearest-even (inputs are finite normals) ----
__device__ inline unsigned short bf_rne(float f) {
    union { float f; uint32_t u; } v; v.f = f;
    uint32_t u = v.u;
    u += 0x7FFFu + ((u >> 16) & 1u);
    return (unsigned short)(u >> 16);
}

// async global->LDS, 16B per lane; LDS dst is wave-uniform base + lane*16
#define GLD_LDS16(gp, lp)                                                     \
    __builtin_amdgcn_global_load_lds(                                         \
        (const __attribute__((address_space(1))) void*)(gp),                  \
        (__attribute__((address_space(3))) void*)(lp), 16, 0, 0)

// ---------------- Fused prologue (unchanged: at memory roofline) ----------------
__global__ __launch_bounds__(256) void prologue_kernel(
    const float4* __restrict__ x4, us4* __restrict__ xbf4,
    const float4* __restrict__ W4,
    const float4* __restrict__ A4,   // [16][1024] float4
    const float* __restrict__ B,     // [4096][16]
    const float* __restrict__ mag,   // [4096]
    unsigned short* __restrict__ wbf,
    float* __restrict__ scale) {
    const int tid = threadIdx.x;
    if (blockIdx.x < 512) {
        const int m0 = blockIdx.x * 8;
        __shared__ float Bs[8][16];
        __shared__ float red[32];
        if (tid < 128) Bs[tid >> 4][tid & 15] = B[m0 * 16 + tid];
        __syncthreads();
        float ss[8] = {};
        for (int c = tid; c < 1024; c += 256) {
            float4 a[16];
#pragma unroll
            for (int r = 0; r < 16; ++r) a[r] = A4[r * 1024 + c];
#pragma unroll
            for (int i = 0; i < 8; ++i) {
                float4 w = W4[(size_t)(m0 + i) * 1024 + c];
#pragma unroll
                for (int r = 0; r < 16; ++r) {
                    const float br = Bs[i][r];
                    w.x += br * a[r].x; w.y += br * a[r].y;
                    w.z += br * a[r].z; w.w += br * a[r].w;
                }
                ss[i] += w.x * w.x + w.y * w.y + w.z * w.z + w.w * w.w;
                us4 o; o[0] = bf_rne(w.x); o[1] = bf_rne(w.y);
                o[2] = bf_rne(w.z); o[3] = bf_rne(w.w);
                *(us4*)&wbf[(size_t)(m0 + i) * 4096 + c * 4] = o;
            }
        }
        const int lane = tid & 63, wv = tid >> 6;
#pragma unroll
        for (int i = 0; i < 8; ++i) {
            float v = ss[i];
#pragma unroll
            for (int off = 32; off > 0; off >>= 1) v += __shfl_down(v, off, 64);
            if (lane == 0) red[wv * 8 + i] = v;
        }
        __syncthreads();
        if (tid < 8) {
            float tot = red[tid] + red[8 + tid] + red[16 + tid] + red[24 + tid];
            scale[m0 + tid] = mag[m0 + tid] / sqrtf(tot);
        }
    } else {
        const size_t base = (size_t)(blockIdx.x - 512) * 1024 + tid;
#pragma unroll
        for (int j = 0; j < 4; ++j) {
            const size_t idx = base + j * 256;
            float4 a = x4[idx];
            us4 o;
            o[0] = bf_rne(a.x); o[1] = bf_rne(a.y);
            o[2] = bf_rne(a.z); o[3] = bf_rne(a.w);
            xbf4[idx] = o;
        }
    }
}

// ---------------- GEMM: C[8192][4096] = xbf @ wbf^T * scale ----------------
// 256x256 tile, BK=64, 8 waves (2M x 4N), 32x32x16 MFMA (2495 TF ceiling vs
// 2075 for 16x16x32). 8-phase / 2 K-tiles schedule, 1 half-tile stage/phase,
// vmcnt(6) only at ph4/ph8. No pre-MFMA lgkm drain: compiler emits fine-grained
// lgkmcnt per consuming MFMA; a free lgkmcnt(0) AFTER the MFMA cluster (reads
// all consumed) preserves the WAR ledger before the closing barrier.
// Stage ledger (iter i, tiles t0=2i/t1=2i+1) — unchanged from R2 (verified):
//   ph1: A1(t1)->buf1; ph2: A0(t0+2)->buf0; ph3: B0(t0+2); ph4: B1(t0+2)
//   ph5: A1(t0+2);     ph6: A0(t1+2)->buf1; ph7: B0(t1+2); ph8: B1(t1+2)
// W4 = vmcnt(6): tile t1 fully landed, {A0,B0,B1}(t0+2) stay in flight.
// W8 = vmcnt(6): tile t0+2 fully landed, {A0,B0,B1}(t1+2) stay in flight.
#define FENCE() asm volatile("" ::: "memory")
#define BAR()   do { FENCE(); __builtin_amdgcn_s_barrier(); FENCE(); } while (0)
#define VMW6()  asm volatile("s_waitcnt vmcnt(6)" ::: "memory")
#define VMW0()  asm volatile("s_waitcnt vmcnt(0)" ::: "memory")
#define LGW0()  asm volatile("s_waitcnt lgkmcnt(0)" ::: "memory")
#define PRIO1() __builtin_amdgcn_s_setprio(1)
#define PRIO0() __builtin_amdgcn_s_setprio(0)

__global__ __launch_bounds__(512, 2) void dora_gemm(
    const unsigned short* __restrict__ xbf,   // [8192][4096] bf16
    const unsigned short* __restrict__ wbf,   // [4096][4096] bf16
    const float* __restrict__ scale,          // [4096]
    float* __restrict__ out) {                // [8192][4096] fp32
    __shared__ __align__(16) unsigned short As[2][256 * 64];
    __shared__ __align__(16) unsigned short Bs[2][256 * 64];

    const int tid  = threadIdx.x;
    const int lane = tid & 63;
    const int w    = tid >> 6;     // wave 0..7
    const int wm   = w >> 2;       // 0..1
    const int wn   = w & 3;        // 0..3
    const int r31  = lane & 31;
    const int hi   = lane >> 5;    // 0..1

    // XCD mapping: 8 XCDs x 64 blocks; each XCD owns an 8M x 8N tile square
    // (bijective over the 32x16 grid); M sweeps fastest within the square.
    const int bid = blockIdx.x;
    const int xcd = bid & 7, sub = bid >> 3;
    const int tileM = (((xcd & 3) << 3) | (sub & 7)) << 8;   // 0..31 * 256
    const int tileN = (((xcd >> 2) << 3) | (sub >> 3)) << 8; // 0..15 * 256

    // staging: thread t, load j covers linear chunk c = j*512 + t of a half-tile
    // (128 rows x 64 bf16). row-in-half = c>>3, phys 16B chunk = c&7; XOR swizzle:
    // phys chunk p of row r holds logical chunk p ^ (r&7) -> pre-swizzled source.
    const int r0 = tid >> 3;              // 0..63
    const int lc = (tid & 7) ^ (r0 & 7);
    const size_t aoff = (size_t)(tileM + r0) * 4096 + lc * 8;
    const size_t boff = (size_t)(tileN + r0) * 4096 + lc * 8;
    const int ld0 = (w * 64) * 8;         // shorts; wave-uniform LDS base, j=0
    const int ld1 = (512 + w * 64) * 8;   // j=1 (+64 rows)

#define STAGE_A(d, h, k0) do {                                                            \
    GLD_LDS16(xbf + aoff + (size_t)((h) * 128) * 4096 + (k0),      &As[d][(h) * 8192 + ld0]); \
    GLD_LDS16(xbf + aoff + (size_t)((h) * 128 + 64) * 4096 + (k0), &As[d][(h) * 8192 + ld1]); \
} while (0)
#define STAGE_B(d, h, k0) do {                                                            \
    GLD_LDS16(wbf + boff + (size_t)((h) * 128) * 4096 + (k0),      &Bs[d][(h) * 8192 + ld0]); \
    GLD_LDS16(wbf + boff + (size_t)((h) * 128 + 64) * 4096 + (k0), &Bs[d][(h) * 8192 + ld1]); \
} while (0)

    // 32x32x16 operand layout: lane reads row/col = lane&31, k = (lane>>5)*8 + j
    // -> 16B chunk index (per K-tile of 64) = kc*2 + (lane>>5), kc = 0..3.
    s16x8 af[2][4];    // A frags [mt][kc], current mh (held across 2 phases)
    s16x8 bfx[2][4];   // B frags [nh][kc], fully resident per K-tile
    f32x16 acc[4][2] = {};   // [mh*2+mt][nh] -> 128 accumulator regs

#define READ_A32(d, mh) do {                                                  \
    _Pragma("unroll") for (int mt = 0; mt < 2; ++mt) {                        \
        const int row = (mh) * 128 + wm * 64 + mt * 32 + r31;                 \
        _Pragma("unroll") for (int kc = 0; kc < 4; ++kc) {                    \
            const int phys = (kc * 2 + hi) ^ (row & 7);                       \
            af[mt][kc] = *(const s16x8*)&As[d][row * 64 + phys * 8];          \
        } } } while (0)
#define READ_B32(d, nh) do {                                                  \
    {   const int row = (nh) * 128 + wn * 32 + r31;                           \
        _Pragma("unroll") for (int kc = 0; kc < 4; ++kc) {                    \
            const int phys = (kc * 2 + hi) ^ (row & 7);                       \
            bfx[nh][kc] = *(const s16x8*)&Bs[d][row * 64 + phys * 8];         \
        } } } while (0)
#define MFMA_Q32(mh, nh) do {                                                 \
    _Pragma("unroll") for (int kc = 0; kc < 4; ++kc)                          \
    _Pragma("unroll") for (int mt = 0; mt < 2; ++mt)                          \
        acc[(mh) * 2 + mt][nh] = __builtin_amdgcn_mfma_f32_32x32x16_bf16(     \
            af[mt][kc], bfx[nh][kc], acc[(mh) * 2 + mt][nh], 0, 0, 0);        \
} while (0)

    // prologue: tile0 full -> buf0, tile1 {A0,B0,B1} -> buf1 (A1(1) staged ph1)
    STAGE_A(0, 0, 0); STAGE_B(0, 0, 0); STAGE_B(0, 1, 0); STAGE_A(0, 1, 0);
    STAGE_A(1, 0, 64); STAGE_B(1, 0, 64); STAGE_B(1, 1, 64);
    VMW6(); BAR();   // tile0 landed; tile1's 3 half-tiles stay in flight

    for (int t0k = 0; t0k < 62 * 64; t0k += 128) {  // tiles t0=2i, t1=2i+1
        const int kA1 = t0k + 64;    // tile 2i+1 (its A1, staged ph1)
        const int kn2 = t0k + 128;   // tile 2i+2 -> buf0
        const int kn3 = t0k + 192;   // tile 2i+3 -> buf1
        // ---- K-tile t0 (buf0) ----
        // ph1: Q(0,0) — 12 ds_read
        READ_A32(0, 0); READ_B32(0, 0);
        STAGE_A(1, 1, kA1);
        BAR();
        PRIO1(); MFMA_Q32(0, 0); PRIO0();
        LGW0(); BAR();
        // ph2: Q(0,1) — 4 ds_read (A held)
        READ_B32(0, 1);
        STAGE_A(0, 0, kn2);
        BAR();
        PRIO1(); MFMA_Q32(0, 1); PRIO0();
        LGW0(); BAR();
        // ph3: Q(1,1) — 8 ds_read (B held)
        READ_A32(0, 1);
        STAGE_B(0, 0, kn2);
        BAR();
        PRIO1(); MFMA_Q32(1, 1); PRIO0();
        LGW0(); BAR();
        // ph4: Q(1,0) — 0 ds_read; W4
        STAGE_B(0, 1, kn2);
        VMW6(); BAR();
        PRIO1(); MFMA_Q32(1, 0); PRIO0();
        BAR();
        // ---- K-tile t1 (buf1) ----
        // ph5: Q(0,0)
        READ_A32(1, 0); READ_B32(1, 0);
        STAGE_A(0, 1, kn2);
        BAR();
        PRIO1(); MFMA_Q32(0, 0); PRIO0();
        LGW0(); BAR();
        // ph6: Q(0,1)
        READ_B32(1, 1);
        STAGE_A(1, 0, kn3);
        BAR();
        PRIO1(); MFMA_Q32(0, 1); PRIO0();
        LGW0(); BAR();
        // ph7: Q(1,1)
        READ_A32(1, 1);
        STAGE_B(1, 0, kn3);
        BAR();
        PRIO1(); MFMA_Q32(1, 1); PRIO0();
        LGW0(); BAR();
        // ph8: Q(1,0); W8
        STAGE_B(1, 1, kn3);
        VMW6(); BAR();
        PRIO1(); MFMA_Q32(1, 0); PRIO0();
        BAR();
    }

    // ---- peeled tiles 62 (buf0) / 63 (buf1) ----
    // entering: tile62 landed (W8 of last iter); {A0,B0,B1}(63) in flight
    READ_A32(0, 0); READ_B32(0, 0);
    STAGE_A(1, 1, 63 * 64);          // A1(63)
    BAR();
    PRIO1(); MFMA_Q32(0, 0); PRIO0();
    LGW0(); BAR();
    READ_B32(0, 1);
    BAR();
    PRIO1(); MFMA_Q32(0, 1); PRIO0();
    LGW0(); BAR();
    READ_A32(0, 1);
    BAR();
    PRIO1(); MFMA_Q32(1, 1); PRIO0();
    LGW0(); BAR();
    VMW0(); BAR();                   // tile 63 fully landed
    PRIO1(); MFMA_Q32(1, 0); PRIO0();
    BAR();
    READ_A32(1, 0); READ_B32(1, 0);
    BAR();
    PRIO1(); MFMA_Q32(0, 0); PRIO0();
    LGW0(); BAR();
    READ_B32(1, 1);
    BAR();
    PRIO1(); MFMA_Q32(0, 1); PRIO0();
    LGW0(); BAR();
    READ_A32(1, 1);
    MFMA_Q32(1, 1);
    MFMA_Q32(1, 0);

    // epilogue: 32x32 C/D layout: col=lane&31, row=(reg&3)+8*(reg>>2)+4*(lane>>5)
#pragma unroll
    for (int nh = 0; nh < 2; ++nh) {
        const int col = tileN + nh * 128 + wn * 32 + r31;
        const float s = scale[col];
#pragma unroll
        for (int mh = 0; mh < 2; ++mh)
#pragma unroll
        for (int mt = 0; mt < 2; ++mt) {
            const int rbase = tileM + mh * 128 + wm * 64 + mt * 32 + hi * 4;
            const f32x16 a = acc[mh * 2 + mt][nh];
#pragma unroll
            for (int reg = 0; reg < 16; ++reg) {
                const int row = rbase + (reg & 3) + ((reg >> 2) << 3);
                out[(size_t)row * 4096 + col] = a[reg] * s;
            }
        }
    }
}

extern "C" void kernel_launch(void* const* d_in, const int* in_sizes, int n_in,
                              void* d_out, int out_size, void* d_ws, size_t ws_size,
                              hipStream_t stream) {
    const float* x   = (const float*)d_in[0];   // [4,2048,4096]
    const float* W   = (const float*)d_in[1];   // [4096,4096]
    const float* A   = (const float*)d_in[2];   // [16,4096]
    const float* B   = (const float*)d_in[3];   // [4096,16]
    const float* mag = (const float*)d_in[4];   // [4096]
    float* out = (float*)d_out;

    const size_t XBF_BYTES = (size_t)8192 * 4096 * 2;  // 67,108,864
    const size_t WBF_BYTES = (size_t)4096 * 4096 * 2;  // 33,554,432
    const size_t NEEDED = XBF_BYTES + WBF_BYTES + 4096 * sizeof(float);
    if (ws_size < NEEDED) return;

    unsigned short* xbf = (unsigned short*)d_ws;
    unsigned short* wbf = (unsigned short*)((char*)d_ws + XBF_BYTES);
    float* scale = (float*)((char*)d_ws + XBF_BYTES + WBF_BYTES);

    prologue_kernel<<<8704, 256, 0, stream>>>((const float4*)x, (us4*)xbf,
                                              (const float4*)W, (const float4*)A,
                                              B, mag, wbf, scale);
    dora_gemm<<<512, 512, 0, stream>>>(xbf, wbf, scale, out);
}

// Round 4
// 313.238 us; speedup vs baseline: 1.1782x; 1.1782x over previous
//
#include <hip/hip_runtime.h>
#include <hip/hip_bf16.h>
#include <stdint.h>

typedef __attribute__((ext_vector_type(8))) short s16x8;    // bf16 MFMA A/B frag (4 VGPRs)
typedef __attribute__((ext_vector_type(4))) float f32x4;    // MFMA C/D frag
typedef __attribute__((ext_vector_type(4))) unsigned short us4;

// ---- bf16 round-to-nearest-even (inputs are finite normals) ----
__device__ inline unsigned short bf_rne(float f) {
    union { float f; uint32_t u; } v; v.f = f;
    uint32_t u = v.u;
    u += 0x7FFFu + ((u >> 16) & 1u);
    return (unsigned short)(u >> 16);
}

// async global->LDS, 16B per lane; LDS dst is wave-uniform base + lane*16
#define GLD_LDS16(gp, lp)                                                     \
    __builtin_amdgcn_global_load_lds(                                         \
        (const __attribute__((address_space(1))) void*)(gp),                  \
        (__attribute__((address_space(3))) void*)(lp), 16, 0, 0)

// generic (__shared__) pointer -> 32-bit LDS byte offset for ds_read vaddr
#define LDSOFF(p) ((unsigned)(uintptr_t)(__attribute__((address_space(3))) const void*)(p))

// ---------------- Fused prologue (unchanged: at memory roofline) ----------------
__global__ __launch_bounds__(256) void prologue_kernel(
    const float4* __restrict__ x4, us4* __restrict__ xbf4,
    const float4* __restrict__ W4,
    const float4* __restrict__ A4,   // [16][1024] float4
    const float* __restrict__ B,     // [4096][16]
    const float* __restrict__ mag,   // [4096]
    unsigned short* __restrict__ wbf,
    float* __restrict__ scale) {
    const int tid = threadIdx.x;
    if (blockIdx.x < 512) {
        const int m0 = blockIdx.x * 8;
        __shared__ float Bs[8][16];
        __shared__ float red[32];
        if (tid < 128) Bs[tid >> 4][tid & 15] = B[m0 * 16 + tid];
        __syncthreads();
        float ss[8] = {};
        for (int c = tid; c < 1024; c += 256) {
            float4 a[16];
#pragma unroll
            for (int r = 0; r < 16; ++r) a[r] = A4[r * 1024 + c];
#pragma unroll
            for (int i = 0; i < 8; ++i) {
                float4 w = W4[(size_t)(m0 + i) * 1024 + c];
#pragma unroll
                for (int r = 0; r < 16; ++r) {
                    const float br = Bs[i][r];
                    w.x += br * a[r].x; w.y += br * a[r].y;
                    w.z += br * a[r].z; w.w += br * a[r].w;
                }
                ss[i] += w.x * w.x + w.y * w.y + w.z * w.z + w.w * w.w;
                us4 o; o[0] = bf_rne(w.x); o[1] = bf_rne(w.y);
                o[2] = bf_rne(w.z); o[3] = bf_rne(w.w);
                *(us4*)&wbf[(size_t)(m0 + i) * 4096 + c * 4] = o;
            }
        }
        const int lane = tid & 63, wv = tid >> 6;
#pragma unroll
        for (int i = 0; i < 8; ++i) {
            float v = ss[i];
#pragma unroll
            for (int off = 32; off > 0; off >>= 1) v += __shfl_down(v, off, 64);
            if (lane == 0) red[wv * 8 + i] = v;
        }
        __syncthreads();
        if (tid < 8) {
            float tot = red[tid] + red[8 + tid] + red[16 + tid] + red[24 + tid];
            scale[m0 + tid] = mag[m0 + tid] / sqrtf(tot);
        }
    } else {
        const size_t base = (size_t)(blockIdx.x - 512) * 1024 + tid;
#pragma unroll
        for (int j = 0; j < 4; ++j) {
            const size_t idx = base + j * 256;
            float4 a = x4[idx];
            us4 o;
            o[0] = bf_rne(a.x); o[1] = bf_rne(a.y);
            o[2] = bf_rne(a.z); o[3] = bf_rne(a.w);
            xbf4[idx] = o;
        }
    }
}

// ---------------- GEMM: C[8192][4096] = xbf @ wbf^T * scale ----------------
// 256x256 tile, BK=64, 8 waves (2M x 4N), 16x16x32 MFMA (R2 structure: proven
// 0 bank conflicts; 32x32 shape is structurally 4-way conflicted - R3 errata).
// 8-phase / 2 K-tiles schedule, vmcnt(6) only at ph4/ph8 (R2 ledger, verified).
// NEW (R4): ds_read addressing fully precomputed - 12 per-lane base addresses
// (8 A, 4 B); mh/nh select = +16384 imm, buffer select = +32768 imm. Reads are
// inline-asm ds_read_b128 vaddr offset:IMM -> zero per-phase VALU addressing.
// Rule 18: every pre-MFMA lgkmcnt(0) is followed by sched_barrier(0).
#define FENCE() asm volatile("" ::: "memory")
#define BAR()   do { FENCE(); __builtin_amdgcn_s_barrier(); FENCE(); } while (0)
#define VMW6()  asm volatile("s_waitcnt vmcnt(6)" ::: "memory")
#define VMW0()  asm volatile("s_waitcnt vmcnt(0)" ::: "memory")
#define LGW8()  asm volatile("s_waitcnt lgkmcnt(8)" ::: "memory")
#define LGW0()  asm volatile("s_waitcnt lgkmcnt(0)" ::: "memory")
#define SB0()   __builtin_amdgcn_sched_barrier(0)
#define PRIO1() __builtin_amdgcn_s_setprio(1)
#define PRIO0() __builtin_amdgcn_s_setprio(0)

// precomputed-address LDS read: vaddr VGPR + literal offset immediate
#define DSR(dst, va, IMM) \
    asm volatile("ds_read_b128 %0, %1 offset:" #IMM : "=v"(dst) : "v"(va))

__global__ __launch_bounds__(512, 2) void dora_gemm(
    const unsigned short* __restrict__ xbf,   // [8192][4096] bf16
    const unsigned short* __restrict__ wbf,   // [4096][4096] bf16
    const float* __restrict__ scale,          // [4096]
    float* __restrict__ out) {                // [8192][4096] fp32
    __shared__ __align__(16) unsigned short As[2][256 * 64];
    __shared__ __align__(16) unsigned short Bs[2][256 * 64];

    const int tid  = threadIdx.x;
    const int lane = tid & 63;
    const int w    = tid >> 6;     // wave 0..7
    const int wm   = w >> 2;       // 0..1
    const int wn   = w & 3;        // 0..3
    const int q    = lane >> 4;
    const int c15  = lane & 15;

    // XCD mapping: 8 XCDs x 64 blocks; each XCD owns an 8M x 8N tile square
    // (bijective over the 32x16 grid); M sweeps fastest within the square.
    const int bid = blockIdx.x;
    const int xcd = bid & 7, sub = bid >> 3;
    const int tileM = (((xcd & 3) << 3) | (sub & 7)) << 8;   // 0..31 * 256
    const int tileN = (((xcd >> 2) << 3) | (sub >> 3)) << 8; // 0..15 * 256

    // staging: thread t, load j covers linear chunk c = j*512 + t of a half-tile
    // (128 rows x 64 bf16). row-in-half = c>>3, phys 16B chunk = c&7; XOR swizzle:
    // phys chunk p of row r holds logical chunk p ^ (r&7) -> pre-swizzled source.
    const int r0 = tid >> 3;              // 0..63
    const int lc = (tid & 7) ^ (r0 & 7);
    const size_t aoff = (size_t)(tileM + r0) * 4096 + lc * 8;
    const size_t boff = (size_t)(tileN + r0) * 4096 + lc * 8;
    const int ld0 = (w * 64) * 8;         // shorts; wave-uniform LDS base, j=0
    const int ld1 = (512 + w * 64) * 8;   // j=1 (+64 rows)

#define STAGE_A(d, h, k0) do {                                                            \
    GLD_LDS16(xbf + aoff + (size_t)((h) * 128) * 4096 + (k0),      &As[d][(h) * 8192 + ld0]); \
    GLD_LDS16(xbf + aoff + (size_t)((h) * 128 + 64) * 4096 + (k0), &As[d][(h) * 8192 + ld1]); \
} while (0)
#define STAGE_B(d, h, k0) do {                                                            \
    GLD_LDS16(wbf + boff + (size_t)((h) * 128) * 4096 + (k0),      &Bs[d][(h) * 8192 + ld0]); \
    GLD_LDS16(wbf + boff + (size_t)((h) * 128 + 64) * 4096 + (k0), &Bs[d][(h) * 8192 + ld1]); \
} while (0)

    // Precomputed ds_read base addresses (buf0, mh0/nh0). For every frag,
    // row&7 == c15&7, so phys = (kc*4+q)^(c15&7) is row-independent.
    const int rb = c15 & 7;
    unsigned aA[4][2], aB[2][2];
#pragma unroll
    for (int mt = 0; mt < 4; ++mt)
#pragma unroll
        for (int kc = 0; kc < 2; ++kc)
            aA[mt][kc] = LDSOFF(&As[0][(wm * 64 + mt * 16 + c15) * 64 +
                                       ((kc * 4 + q) ^ rb) * 8]);
#pragma unroll
    for (int nt = 0; nt < 2; ++nt)
#pragma unroll
        for (int kc = 0; kc < 2; ++kc)
            aB[nt][kc] = LDSOFF(&Bs[0][(wn * 32 + nt * 16 + c15) * 64 +
                                       ((kc * 4 + q) ^ rb) * 8]);

    s16x8 af[4][2];      // A frags [mt][kc], current mh (held across 2 phases)
    s16x8 bfx[2][2][2];  // B frags [nh][nt][kc], fully resident per K-tile
    f32x4 acc[8][4] = {};

    // IMM encodes (buffer, half): buf = +32768, mh/nh = +16384
#define RD_A(IMM) do {                                                        \
    DSR(af[0][0], aA[0][0], IMM); DSR(af[0][1], aA[0][1], IMM);               \
    DSR(af[1][0], aA[1][0], IMM); DSR(af[1][1], aA[1][1], IMM);               \
    DSR(af[2][0], aA[2][0], IMM); DSR(af[2][1], aA[2][1], IMM);               \
    DSR(af[3][0], aA[3][0], IMM); DSR(af[3][1], aA[3][1], IMM); } while (0)
#define RD_B(nh, IMM) do {                                                    \
    DSR(bfx[nh][0][0], aB[0][0], IMM); DSR(bfx[nh][0][1], aB[0][1], IMM);     \
    DSR(bfx[nh][1][0], aB[1][0], IMM); DSR(bfx[nh][1][1], aB[1][1], IMM); } while (0)

#define MFMA_Q(mh, nh) do {                                                   \
    _Pragma("unroll") for (int mt = 0; mt < 4; ++mt)                          \
    _Pragma("unroll") for (int nt = 0; nt < 2; ++nt)                          \
    _Pragma("unroll") for (int kc = 0; kc < 2; ++kc)                          \
        acc[(mh) * 4 + mt][(nh) * 2 + nt] =                                   \
            __builtin_amdgcn_mfma_f32_16x16x32_bf16(                          \
                af[mt][kc], bfx[nh][nt][kc],                                  \
                acc[(mh) * 4 + mt][(nh) * 2 + nt], 0, 0, 0);                  \
} while (0)

    // prologue: tile0 full -> buf0, tile1 {A0,B0,B1} -> buf1 (A1(1) staged ph1)
    STAGE_A(0, 0, 0); STAGE_B(0, 0, 0); STAGE_B(0, 1, 0); STAGE_A(0, 1, 0);
    STAGE_A(1, 0, 64); STAGE_B(1, 0, 64); STAGE_B(1, 1, 64);
    VMW6(); BAR();   // tile0 landed; tile1's 3 half-tiles stay in flight

    for (int t0k = 0; t0k < 62 * 64; t0k += 128) {  // tiles t0=2i, t1=2i+1
        const int kA1 = t0k + 64;    // tile 2i+1 (its A1, staged ph1)
        const int kn2 = t0k + 128;   // tile 2i+2 -> buf0
        const int kn3 = t0k + 192;   // tile 2i+3 -> buf1
        // ---- K-tile t0 (buf0) ----
        // ph1: Q(0,0) — 12 ds_read
        RD_A(0); RD_B(0, 0);
        STAGE_A(1, 1, kA1);
        LGW8(); BAR(); LGW0(); SB0();
        PRIO1(); MFMA_Q(0, 0); PRIO0(); BAR();
        // ph2: Q(0,1) — 4 ds_read (A held)
        RD_B(1, 16384);
        STAGE_A(0, 0, kn2);
        BAR(); LGW0(); SB0();
        PRIO1(); MFMA_Q(0, 1); PRIO0(); BAR();
        // ph3: Q(1,1) — 8 ds_read (B held)
        RD_A(16384);
        STAGE_B(0, 0, kn2);
        BAR(); LGW0(); SB0();
        PRIO1(); MFMA_Q(1, 1); PRIO0(); BAR();
        // ph4: Q(1,0) — 0 ds_read (A1, B0 resident); W4
        STAGE_B(0, 1, kn2);
        VMW6(); BAR();
        PRIO1(); MFMA_Q(1, 0); PRIO0(); BAR();
        // ---- K-tile t1 (buf1) ----
        // ph5: Q(0,0)
        RD_A(32768); RD_B(0, 32768);
        STAGE_A(0, 1, kn2);
        LGW8(); BAR(); LGW0(); SB0();
        PRIO1(); MFMA_Q(0, 0); PRIO0(); BAR();
        // ph6: Q(0,1)
        RD_B(1, 49152);
        STAGE_A(1, 0, kn3);
        BAR(); LGW0(); SB0();
        PRIO1(); MFMA_Q(0, 1); PRIO0(); BAR();
        // ph7: Q(1,1)
        RD_A(49152);
        STAGE_B(1, 0, kn3);
        BAR(); LGW0(); SB0();
        PRIO1(); MFMA_Q(1, 1); PRIO0(); BAR();
        // ph8: Q(1,0); W8
        STAGE_B(1, 1, kn3);
        VMW6(); BAR();
        PRIO1(); MFMA_Q(1, 0); PRIO0(); BAR();
    }

    // ---- peeled tiles 62 (buf0) / 63 (buf1) ----
    // entering: tile62 landed (W8 of last iter); {A0,B0,B1}(63) in flight
    RD_A(0); RD_B(0, 0);
    STAGE_A(1, 1, 63 * 64);          // A1(63)
    LGW8(); BAR(); LGW0(); SB0();
    PRIO1(); MFMA_Q(0, 0); PRIO0(); BAR();
    RD_B(1, 16384);
    BAR(); LGW0(); SB0();
    PRIO1(); MFMA_Q(0, 1); PRIO0(); BAR();
    RD_A(16384);
    BAR(); LGW0(); SB0();
    PRIO1(); MFMA_Q(1, 1); PRIO0(); BAR();
    VMW0(); BAR();                   // tile 63 fully landed
    PRIO1(); MFMA_Q(1, 0); PRIO0(); BAR();
    RD_A(32768); RD_B(0, 32768);
    BAR(); LGW0(); SB0();
    PRIO1(); MFMA_Q(0, 0); PRIO0(); BAR();
    RD_B(1, 49152);
    BAR(); LGW0(); SB0();
    PRIO1(); MFMA_Q(0, 1); PRIO0(); BAR();
    RD_A(49152);
    LGW0(); SB0();
    PRIO1(); MFMA_Q(1, 1); PRIO0();
    MFMA_Q(1, 0);

    // epilogue: C/D layout col=lane&15, row=(lane>>4)*4+reg ; scale by mag/norm
#pragma unroll
    for (int nh = 0; nh < 2; ++nh)
#pragma unroll
    for (int nt = 0; nt < 2; ++nt) {
        const int col = tileN + nh * 128 + wn * 32 + nt * 16 + c15;
        const float s = scale[col];
#pragma unroll
        for (int mh = 0; mh < 2; ++mh)
#pragma unroll
        for (int mt = 0; mt < 4; ++mt) {
            const int row0 = tileM + mh * 128 + wm * 64 + mt * 16 + q * 4;
#pragma unroll
            for (int r = 0; r < 4; ++r)
                out[(size_t)(row0 + r) * 4096 + col] = acc[mh * 4 + mt][nh * 2 + nt][r] * s;
        }
    }
}

extern "C" void kernel_launch(void* const* d_in, const int* in_sizes, int n_in,
                              void* d_out, int out_size, void* d_ws, size_t ws_size,
                              hipStream_t stream) {
    const float* x   = (const float*)d_in[0];   // [4,2048,4096]
    const float* W   = (const float*)d_in[1];   // [4096,4096]
    const float* A   = (const float*)d_in[2];   // [16,4096]
    const float* B   = (const float*)d_in[3];   // [4096,16]
    const float* mag = (const float*)d_in[4];   // [4096]
    float* out = (float*)d_out;

    const size_t XBF_BYTES = (size_t)8192 * 4096 * 2;  // 67,108,864
    const size_t WBF_BYTES = (size_t)4096 * 4096 * 2;  // 33,554,432
    const size_t NEEDED = XBF_BYTES + WBF_BYTES + 4096 * sizeof(float);
    if (ws_size < NEEDED) return;

    unsigned short* xbf = (unsigned short*)d_ws;
    unsigned short* wbf = (unsigned short*)((char*)d_ws + XBF_BYTES);
    float* scale = (float*)((char*)d_ws + XBF_BYTES + WBF_BYTES);

    prologue_kernel<<<8704, 256, 0, stream>>>((const float4*)x, (us4*)xbf,
                                              (const float4*)W, (const float4*)A,
                                              B, mag, wbf, scale);
    dora_gemm<<<512, 512, 0, stream>>>(xbf, wbf, scale, out);
}

// Round 5
// 303.635 us; speedup vs baseline: 1.2155x; 1.0316x over previous
//
#include <hip/hip_runtime.h>
#include <hip/hip_bf16.h>
#include <stdint.h>

typedef __attribute__((ext_vector_type(8))) short s16x8;    // bf16 MFMA A/B frag (4 VGPRs)
typedef __attribute__((ext_vector_type(4))) float f32x4;    // MFMA C/D frag
typedef __attribute__((ext_vector_type(4))) unsigned short us4;

// ---- bf16 round-to-nearest-even (inputs are finite normals) ----
__device__ inline unsigned short bf_rne(float f) {
    union { float f; uint32_t u; } v; v.f = f;
    uint32_t u = v.u;
    u += 0x7FFFu + ((u >> 16) & 1u);
    return (unsigned short)(u >> 16);
}

// async global->LDS, 16B per lane; LDS dst is wave-uniform base + lane*16
#define GLD_LDS16(gp, lp)                                                     \
    __builtin_amdgcn_global_load_lds(                                         \
        (const __attribute__((address_space(1))) void*)(gp),                  \
        (__attribute__((address_space(3))) void*)(lp), 16, 0, 0)

// generic (__shared__) pointer -> 32-bit LDS byte offset for ds_read vaddr
#define LDSOFF(p) ((unsigned)(uintptr_t)(__attribute__((address_space(3))) const void*)(p))

// ---------------- Fused prologue (unchanged: at memory roofline) ----------------
__global__ __launch_bounds__(256) void prologue_kernel(
    const float4* __restrict__ x4, us4* __restrict__ xbf4,
    const float4* __restrict__ W4,
    const float4* __restrict__ A4,   // [16][1024] float4
    const float* __restrict__ B,     // [4096][16]
    const float* __restrict__ mag,   // [4096]
    unsigned short* __restrict__ wbf,
    float* __restrict__ scale) {
    const int tid = threadIdx.x;
    if (blockIdx.x < 512) {
        const int m0 = blockIdx.x * 8;
        __shared__ float Bs[8][16];
        __shared__ float red[32];
        if (tid < 128) Bs[tid >> 4][tid & 15] = B[m0 * 16 + tid];
        __syncthreads();
        float ss[8] = {};
        for (int c = tid; c < 1024; c += 256) {
            float4 a[16];
#pragma unroll
            for (int r = 0; r < 16; ++r) a[r] = A4[r * 1024 + c];
#pragma unroll
            for (int i = 0; i < 8; ++i) {
                float4 w = W4[(size_t)(m0 + i) * 1024 + c];
#pragma unroll
                for (int r = 0; r < 16; ++r) {
                    const float br = Bs[i][r];
                    w.x += br * a[r].x; w.y += br * a[r].y;
                    w.z += br * a[r].z; w.w += br * a[r].w;
                }
                ss[i] += w.x * w.x + w.y * w.y + w.z * w.z + w.w * w.w;
                us4 o; o[0] = bf_rne(w.x); o[1] = bf_rne(w.y);
                o[2] = bf_rne(w.z); o[3] = bf_rne(w.w);
                *(us4*)&wbf[(size_t)(m0 + i) * 4096 + c * 4] = o;
            }
        }
        const int lane = tid & 63, wv = tid >> 6;
#pragma unroll
        for (int i = 0; i < 8; ++i) {
            float v = ss[i];
#pragma unroll
            for (int off = 32; off > 0; off >>= 1) v += __shfl_down(v, off, 64);
            if (lane == 0) red[wv * 8 + i] = v;
        }
        __syncthreads();
        if (tid < 8) {
            float tot = red[tid] + red[8 + tid] + red[16 + tid] + red[24 + tid];
            scale[m0 + tid] = mag[m0 + tid] / sqrtf(tot);
        }
    } else {
        const size_t base = (size_t)(blockIdx.x - 512) * 1024 + tid;
#pragma unroll
        for (int j = 0; j < 4; ++j) {
            const size_t idx = base + j * 256;
            float4 a = x4[idx];
            us4 o;
            o[0] = bf_rne(a.x); o[1] = bf_rne(a.y);
            o[2] = bf_rne(a.z); o[3] = bf_rne(a.w);
            xbf4[idx] = o;
        }
    }
}

// ---------------- GEMM: C[8192][4096] = xbf @ wbf^T * scale ----------------
// 256x256 tile, BK=64, 8 waves (2M x 4N), 16x16x32 MFMA, precomputed-address
// inline-asm ds_read_b128 (R4, 0 bank conflicts). NEW (R5): ONE barrier per
// phase. The post-MFMA barrier existed only to allow stages into regions read
// 1 phase earlier; reordered stage ledger gives every stage >=2-phase distance
// from its region's last reader, which single-barrier semantics protect:
// a wave crossing BAR_{p+1} has executed its phase-p LGW0 (reads drained).
// Stage ledger (iter i, t0=2i, t1=2i+1):
//   ph1: B1(t1)->buf1   [buf1.B1 last read ph6 of iter i-1; ph1_i = +3]
//   ph2: A1(t1)->buf1   [last read ph7 i-1; +3]
//   ph3: A0(t0+2)->buf0 [last read ph1; +2]   ph4: B0(t0+2) [ph1; +3]
//   ph5: B1(t0+2)->buf0 [last read ph2; +3]   ph6: A1(t0+2) [ph3; +3]
//   ph7: A0(t1+2)->buf1 [last read ph5; +2]   ph8: B0(t1+2) [ph5; +3]
// RAW coverage, vmcnt(4) at ph4/ph8 (leaves the 2 newest stages in flight):
//   W4 lands <=ph2: A0,B0(t1)[ph7,8 prev] for ph5; B1(t1)[ph1] for ph6;
//                   A1(t1)[ph2] for ph7.
//   W8 lands <=ph6: A0,B0(t0+2)[ph3,4] for next ph1; B1(t0+2)[ph5] for next
//                   ph2; A1(t0+2)[ph6] for next ph3.
// Every stage gets 3-7 phases (~2300-5400 cyc) to land.
#define FENCE() asm volatile("" ::: "memory")
#define BAR()   do { FENCE(); __builtin_amdgcn_s_barrier(); FENCE(); } while (0)
#define VMW4()  asm volatile("s_waitcnt vmcnt(4)" ::: "memory")
#define VMW0()  asm volatile("s_waitcnt vmcnt(0)" ::: "memory")
#define LGW0()  asm volatile("s_waitcnt lgkmcnt(0)" ::: "memory")
#define SB0()   __builtin_amdgcn_sched_barrier(0)
#define PRIO1() __builtin_amdgcn_s_setprio(1)
#define PRIO0() __builtin_amdgcn_s_setprio(0)

// precomputed-address LDS read: vaddr VGPR + literal offset immediate
#define DSR(dst, va, IMM) \
    asm volatile("ds_read_b128 %0, %1 offset:" #IMM : "=v"(dst) : "v"(va))

__global__ __launch_bounds__(512, 2) void dora_gemm(
    const unsigned short* __restrict__ xbf,   // [8192][4096] bf16
    const unsigned short* __restrict__ wbf,   // [4096][4096] bf16
    const float* __restrict__ scale,          // [4096]
    float* __restrict__ out) {                // [8192][4096] fp32
    __shared__ __align__(16) unsigned short As[2][256 * 64];
    __shared__ __align__(16) unsigned short Bs[2][256 * 64];

    const int tid  = threadIdx.x;
    const int lane = tid & 63;
    const int w    = tid >> 6;     // wave 0..7
    const int wm   = w >> 2;       // 0..1
    const int wn   = w & 3;        // 0..3
    const int q    = lane >> 4;
    const int c15  = lane & 15;

    // XCD mapping: 8 XCDs x 64 blocks; each XCD owns an 8M x 8N tile square
    // (bijective over the 32x16 grid); M sweeps fastest within the square.
    const int bid = blockIdx.x;
    const int xcd = bid & 7, sub = bid >> 3;
    const int tileM = (((xcd & 3) << 3) | (sub & 7)) << 8;   // 0..31 * 256
    const int tileN = (((xcd >> 2) << 3) | (sub >> 3)) << 8; // 0..15 * 256

    // staging: thread t, load j covers linear chunk c = j*512 + t of a half-tile
    // (128 rows x 64 bf16). row-in-half = c>>3, phys 16B chunk = c&7; XOR swizzle:
    // phys chunk p of row r holds logical chunk p ^ (r&7) -> pre-swizzled source.
    const int r0 = tid >> 3;              // 0..63
    const int lc = (tid & 7) ^ (r0 & 7);
    const size_t aoff = (size_t)(tileM + r0) * 4096 + lc * 8;
    const size_t boff = (size_t)(tileN + r0) * 4096 + lc * 8;
    const int ld0 = (w * 64) * 8;         // shorts; wave-uniform LDS base, j=0
    const int ld1 = (512 + w * 64) * 8;   // j=1 (+64 rows)

#define STAGE_A(d, h, k0) do {                                                            \
    GLD_LDS16(xbf + aoff + (size_t)((h) * 128) * 4096 + (k0),      &As[d][(h) * 8192 + ld0]); \
    GLD_LDS16(xbf + aoff + (size_t)((h) * 128 + 64) * 4096 + (k0), &As[d][(h) * 8192 + ld1]); \
} while (0)
#define STAGE_B(d, h, k0) do {                                                            \
    GLD_LDS16(wbf + boff + (size_t)((h) * 128) * 4096 + (k0),      &Bs[d][(h) * 8192 + ld0]); \
    GLD_LDS16(wbf + boff + (size_t)((h) * 128 + 64) * 4096 + (k0), &Bs[d][(h) * 8192 + ld1]); \
} while (0)

    // Precomputed ds_read base addresses (buf0, mh0/nh0). For every frag,
    // row&7 == c15&7, so phys = (kc*4+q)^(c15&7) is row-independent.
    const int rb = c15 & 7;
    unsigned aA[4][2], aB[2][2];
#pragma unroll
    for (int mt = 0; mt < 4; ++mt)
#pragma unroll
        for (int kc = 0; kc < 2; ++kc)
            aA[mt][kc] = LDSOFF(&As[0][(wm * 64 + mt * 16 + c15) * 64 +
                                       ((kc * 4 + q) ^ rb) * 8]);
#pragma unroll
    for (int nt = 0; nt < 2; ++nt)
#pragma unroll
        for (int kc = 0; kc < 2; ++kc)
            aB[nt][kc] = LDSOFF(&Bs[0][(wn * 32 + nt * 16 + c15) * 64 +
                                       ((kc * 4 + q) ^ rb) * 8]);

    s16x8 af[4][2];      // A frags [mt][kc], current mh (held across 2 phases)
    s16x8 bfx[2][2][2];  // B frags [nh][nt][kc], fully resident per K-tile
    f32x4 acc[8][4] = {};

    // IMM encodes (buffer, half): buf = +32768, mh/nh = +16384
#define RD_A(IMM) do {                                                        \
    DSR(af[0][0], aA[0][0], IMM); DSR(af[0][1], aA[0][1], IMM);               \
    DSR(af[1][0], aA[1][0], IMM); DSR(af[1][1], aA[1][1], IMM);               \
    DSR(af[2][0], aA[2][0], IMM); DSR(af[2][1], aA[2][1], IMM);               \
    DSR(af[3][0], aA[3][0], IMM); DSR(af[3][1], aA[3][1], IMM); } while (0)
#define RD_B(nh, IMM) do {                                                    \
    DSR(bfx[nh][0][0], aB[0][0], IMM); DSR(bfx[nh][0][1], aB[0][1], IMM);     \
    DSR(bfx[nh][1][0], aB[1][0], IMM); DSR(bfx[nh][1][1], aB[1][1], IMM); } while (0)

#define MFMA_Q(mh, nh) do {                                                   \
    _Pragma("unroll") for (int mt = 0; mt < 4; ++mt)                          \
    _Pragma("unroll") for (int nt = 0; nt < 2; ++nt)                          \
    _Pragma("unroll") for (int kc = 0; kc < 2; ++kc)                          \
        acc[(mh) * 4 + mt][(nh) * 2 + nt] =                                   \
            __builtin_amdgcn_mfma_f32_16x16x32_bf16(                          \
                af[mt][kc], bfx[nh][nt][kc],                                  \
                acc[(mh) * 4 + mt][(nh) * 2 + nt], 0, 0, 0);                  \
} while (0)

    // prologue: tile0 {A0,B0,B1,A1} -> buf0; tile1 {A0,B0} -> buf1
    // (B1(t1)/A1(t1) are staged at ph1/ph2 of iter 0, per the steady ledger)
    STAGE_A(0, 0, 0); STAGE_B(0, 0, 0); STAGE_B(0, 1, 0); STAGE_A(0, 1, 0);
    STAGE_A(1, 0, 64); STAGE_B(1, 0, 64);
    VMW4(); BAR();   // tile0 landed; tile1's A0,B0 (4 loads) stay in flight

    for (int t0k = 0; t0k <= 60 * 64; t0k += 128) {  // t0=2i (0..60), t1=2i+1
        const int kt1 = t0k + 64;    // tile t1 (B1/A1 staged ph1/ph2)
        const int kn2 = t0k + 128;   // tile t0+2 -> buf0
        const int kn3 = t0k + 192;   // tile t1+2 -> buf1
        // ph1: Q(0,0) — 12 ds_read
        RD_A(0); RD_B(0, 0);
        STAGE_B(1, 1, kt1);
        BAR(); LGW0(); SB0();
        PRIO1(); MFMA_Q(0, 0); PRIO0();
        // ph2: Q(0,1) — 4 ds_read (A held)
        RD_B(1, 16384);
        STAGE_A(1, 1, kt1);
        BAR(); LGW0(); SB0();
        PRIO1(); MFMA_Q(0, 1); PRIO0();
        // ph3: Q(1,1) — 8 ds_read (B held)
        RD_A(16384);
        STAGE_A(0, 0, kn2);
        BAR(); LGW0(); SB0();
        PRIO1(); MFMA_Q(1, 1); PRIO0();
        // ph4: Q(1,0) — 0 ds_read; W4
        STAGE_B(0, 0, kn2);
        VMW4(); BAR();
        PRIO1(); MFMA_Q(1, 0); PRIO0();
        // ph5: Q(0,0) of t1 (buf1)
        RD_A(32768); RD_B(0, 32768);
        STAGE_B(0, 1, kn2);
        BAR(); LGW0(); SB0();
        PRIO1(); MFMA_Q(0, 0); PRIO0();
        // ph6: Q(0,1)
        RD_B(1, 49152);
        STAGE_A(0, 1, kn2);
        BAR(); LGW0(); SB0();
        PRIO1(); MFMA_Q(0, 1); PRIO0();
        // ph7: Q(1,1)
        RD_A(49152);
        STAGE_A(1, 0, kn3);
        BAR(); LGW0(); SB0();
        PRIO1(); MFMA_Q(1, 1); PRIO0();
        // ph8: Q(1,0); W8
        STAGE_B(1, 0, kn3);
        VMW4(); BAR();
        PRIO1(); MFMA_Q(1, 0); PRIO0();
    }

    // ---- peel: tiles 62 (buf0) / 63 (buf1) ----
    // entering: tile62 fully landed (W8 + BAR of last iter); A0,B0(63) in
    // flight (ph7/ph8 of last iter). Stage B1(63)/A1(63) here (steady ph1/ph2
    // pattern); no barriers needed until the pre-tile-63 full drain.
    RD_A(0); RD_B(0, 0);
    STAGE_B(1, 1, 4032);             // B1(63)
    LGW0(); SB0();
    PRIO1(); MFMA_Q(0, 0); PRIO0();
    RD_B(1, 16384);
    STAGE_A(1, 1, 4032);             // A1(63)
    LGW0(); SB0();
    PRIO1(); MFMA_Q(0, 1); PRIO0();
    RD_A(16384);
    LGW0(); SB0();
    PRIO1(); MFMA_Q(1, 1); MFMA_Q(1, 0); PRIO0();
    VMW0(); BAR();                   // all of tile 63 landed, all waves
    RD_A(32768); RD_B(0, 32768);
    LGW0(); SB0();
    PRIO1(); MFMA_Q(0, 0); PRIO0();
    RD_B(1, 49152);
    LGW0(); SB0();
    PRIO1(); MFMA_Q(0, 1); PRIO0();
    RD_A(49152);
    LGW0(); SB0();
    PRIO1(); MFMA_Q(1, 1); MFMA_Q(1, 0); PRIO0();

    // epilogue: C/D layout col=lane&15, row=(lane>>4)*4+reg ; scale by mag/norm
#pragma unroll
    for (int nh = 0; nh < 2; ++nh)
#pragma unroll
    for (int nt = 0; nt < 2; ++nt) {
        const int col = tileN + nh * 128 + wn * 32 + nt * 16 + c15;
        const float s = scale[col];
#pragma unroll
        for (int mh = 0; mh < 2; ++mh)
#pragma unroll
        for (int mt = 0; mt < 4; ++mt) {
            const int row0 = tileM + mh * 128 + wm * 64 + mt * 16 + q * 4;
#pragma unroll
            for (int r = 0; r < 4; ++r)
                out[(size_t)(row0 + r) * 4096 + col] = acc[mh * 4 + mt][nh * 2 + nt][r] * s;
        }
    }
}

extern "C" void kernel_launch(void* const* d_in, const int* in_sizes, int n_in,
                              void* d_out, int out_size, void* d_ws, size_t ws_size,
                              hipStream_t stream) {
    const float* x   = (const float*)d_in[0];   // [4,2048,4096]
    const float* W   = (const float*)d_in[1];   // [4096,4096]
    const float* A   = (const float*)d_in[2];   // [16,4096]
    const float* B   = (const float*)d_in[3];   // [4096,16]
    const float* mag = (const float*)d_in[4];   // [4096]
    float* out = (float*)d_out;

    const size_t XBF_BYTES = (size_t)8192 * 4096 * 2;  // 67,108,864
    const size_t WBF_BYTES = (size_t)4096 * 4096 * 2;  // 33,554,432
    const size_t NEEDED = XBF_BYTES + WBF_BYTES + 4096 * sizeof(float);
    if (ws_size < NEEDED) return;

    unsigned short* xbf = (unsigned short*)d_ws;
    unsigned short* wbf = (unsigned short*)((char*)d_ws + XBF_BYTES);
    float* scale = (float*)((char*)d_ws + XBF_BYTES + WBF_BYTES);

    prologue_kernel<<<8704, 256, 0, stream>>>((const float4*)x, (us4*)xbf,
                                              (const float4*)W, (const float4*)A,
                                              B, mag, wbf, scale);
    dora_gemm<<<512, 512, 0, stream>>>(xbf, wbf, scale, out);
}